// Round 8
// baseline (974.168 us; speedup 1.0000x reference)
//
#include <hip/hip_runtime.h>

#define C0n 50000
#define C1n 150000
#define C2n 300000
#define E0n 300000
#define E1n 600000
#define NEn (E0n + E1n)

typedef float  v4f    __attribute__((ext_vector_type(4)));
typedef float  v2f    __attribute__((ext_vector_type(2)));
typedef float  f32x4  __attribute__((ext_vector_type(4)));
typedef short  bf16x8 __attribute__((ext_vector_type(8)));
typedef unsigned short u16;

__device__ __forceinline__ u16 f2bf(float f){
    unsigned u = __builtin_bit_cast(unsigned, f);
    u += 0x7FFFu + ((u >> 16) & 1u);          // RNE
    return (u16)(u >> 16);
}
__device__ __forceinline__ float bf2f(u16 h){
    unsigned u = ((unsigned)h) << 16;
    return __builtin_bit_cast(float, u);
}
__device__ __forceinline__ f32x4 mfma16(bf16x8 a, bf16x8 b, f32x4 c){
    return __builtin_amdgcn_mfma_f32_16x16x32_bf16(a, b, c, 0, 0, 0);
}
__device__ __forceinline__ float red16(float v){
    v += __shfl_xor(v, 1); v += __shfl_xor(v, 2);
    v += __shfl_xor(v, 4); v += __shfl_xor(v, 8);
    return v;
}
// 8 consecutive f32 -> bf16x8 fragment (16B-aligned source)
__device__ __forceinline__ bf16x8 frag8(const float* __restrict__ p){
    v4f a = *(const v4f*)p, b = *(const v4f*)(p + 4);
    bf16x8 r;
    r[0] = (short)f2bf(a[0]); r[1] = (short)f2bf(a[1]);
    r[2] = (short)f2bf(a[2]); r[3] = (short)f2bf(a[3]);
    r[4] = (short)f2bf(b[0]); r[5] = (short)f2bf(b[1]);
    r[6] = (short)f2bf(b[2]); r[7] = (short)f2bf(b[3]);
    return r;
}

// ------- xp_t = relu(x @ Wp[t] + bp[t]) for ALL t, x read once -------
__global__ __launch_bounds__(256) void k_projm3(const float* __restrict__ x,
    const float* __restrict__ Wp, const float* __restrict__ bp,
    u16* __restrict__ xp3)
{
    __shared__ u16 Wt[3][64 * 72];   // [t][c][k], pad to 72
    __shared__ float bps[3 * 64];
    const int tid = threadIdx.x;
    for (int i = tid; i < 192; i += 256) bps[i] = bp[i];
    for (int t = 0; t < 3; t++)
        for (int idx = tid; idx < 64 * 64; idx += 256) {
            int k = idx >> 6, c = idx & 63;      // idx = k*64 + c
            Wt[t][c * 72 + k] = f2bf(Wp[t * 4096 + idx]);
        }
    __syncthreads();

    const int lane = tid & 63, wid = tid >> 6;
    const int lr = lane & 15, lg = lane >> 4;
    const int ntiles = C2n / 16;                  // 18750
    int rt = blockIdx.x * 4 + wid;
    const bool valid = (rt < ntiles);
    if (rt > ntiles - 1) rt = ntiles - 1;         // clamp for loads only
    const int r0 = rt * 16;

    // x fragments: t-invariant, load once
    bf16x8 xa[2];
    xa[0] = frag8(&x[(size_t)(r0 + lr) * 64 + 0  + 8 * lg]);
    xa[1] = frag8(&x[(size_t)(r0 + lr) * 64 + 32 + 8 * lg]);

    for (int t = 0; t < 3; t++) {
        f32x4 acc[4];
#pragma unroll
        for (int n = 0; n < 4; n++) acc[n] = 0;
#pragma unroll
        for (int ks = 0; ks < 2; ks++) {
#pragma unroll
            for (int n = 0; n < 4; n++) {
                bf16x8 b = *(const bf16x8*)&Wt[t][(16 * n + lr) * 72 + ks * 32 + 8 * lg];
                acc[n] = mfma16(xa[ks], b, acc[n]);
            }
        }
        if (valid) {
            u16* xp = xp3 + (size_t)t * C2n * 64;
#pragma unroll
            for (int n = 0; n < 4; n++) {
                const float bb = bps[t * 64 + 16 * n + lr];
#pragma unroll
                for (int j = 0; j < 4; j++)
                    xp[(size_t)(r0 + 4 * lg + j) * 64 + 16 * n + lr] =
                        f2bf(fmaxf(acc[n][j] + bb, 0.f));
            }
        }
    }
}

// ---------------- CSR build: histogram ----------------
__global__ __launch_bounds__(256) void k_hist(const int* __restrict__ d0,
    const int* __restrict__ d1, const int* __restrict__ d2,
    int* __restrict__ deg, int nE, int nV)
{
    const int e = blockIdx.x * 256 + threadIdx.x;
    if (e >= nE) return;
    const int y = blockIdx.y;
    const int* d = (y == 0) ? d0 : (y == 1) ? d1 : d2;
    atomicAdd(&deg[(size_t)y * nV + d[e]], 1);
}

// ---------------- CSR build: exclusive scan ----------------
__global__ __launch_bounds__(256) void k_scan_a(int* __restrict__ a, int n,
    int* __restrict__ bsum, int nblk)
{
    __shared__ int sd[256];
    const int t = threadIdx.x, y = blockIdx.y;
    int* arr = a + (size_t)y * n;
    const int base = blockIdx.x * 2048 + t * 8;
    int v[8];
#pragma unroll
    for (int j = 0; j < 8; j++) v[j] = (base + j < n) ? arr[base + j] : 0;
    int tot = 0;
#pragma unroll
    for (int j = 0; j < 8; j++) { int tmp = v[j]; v[j] = tot; tot += tmp; }
    sd[t] = tot; __syncthreads();
    for (int off = 1; off < 256; off <<= 1) {
        int xv = (t >= off) ? sd[t - off] : 0;
        __syncthreads();
        sd[t] += xv;
        __syncthreads();
    }
    const int excl = sd[t] - tot;
#pragma unroll
    for (int j = 0; j < 8; j++)
        if (base + j < n) arr[base + j] = excl + v[j];
    if (t == 255) bsum[y * nblk + blockIdx.x] = sd[255];
}

__global__ __launch_bounds__(256) void k_scan_b(int* __restrict__ bsum, int nblk)
{
    __shared__ int sd[256];
    const int t = threadIdx.x, y = blockIdx.y;
    int val = (t < nblk) ? bsum[y * nblk + t] : 0;
    sd[t] = val; __syncthreads();
    for (int off = 1; off < 256; off <<= 1) {
        int xv = (t >= off) ? sd[t - off] : 0;
        __syncthreads();
        sd[t] += xv;
        __syncthreads();
    }
    if (t < nblk) bsum[y * nblk + t] = sd[t] - val;
}

__global__ __launch_bounds__(256) void k_scan_c(int* __restrict__ a, int n,
    const int* __restrict__ bsum, int nblk)
{
    const int t = threadIdx.x, y = blockIdx.y;
    int* arr = a + (size_t)y * n;
    const int base = blockIdx.x * 2048 + t * 8;
    const int add = bsum[y * nblk + blockIdx.x];
#pragma unroll
    for (int j = 0; j < 8; j++)
        if (base + j < n) arr[base + j] += add;
}

// ---------------- CSR build: fill ----------------
__global__ __launch_bounds__(256) void k_fill(const int* __restrict__ s0,
    const int* __restrict__ s1, const int* __restrict__ s2,
    const int* __restrict__ d0, const int* __restrict__ d1, const int* __restrict__ d2,
    const int* __restrict__ rp, int* __restrict__ fill, int* __restrict__ el,
    int nE, int nV)
{
    const int e = blockIdx.x * 256 + threadIdx.x;
    if (e >= nE) return;
    const int y = blockIdx.y;
    const int* s = (y == 0) ? s0 : (y == 1) ? s1 : s2;
    const int* d = (y == 0) ? d0 : (y == 1) ? d1 : d2;
    const int dd = d[e];
    const int pos = rp[(size_t)y * nV + dd] + atomicAdd(&fill[(size_t)y * nV + dd], 1);
    el[(size_t)y * nE + pos] = s[e];
}

// ---------------- gather layer1: agg_t[r] = mean of xp_t[src] (bf16 -> bf16) ----------------
__global__ __launch_bounds__(256) void k_gath1(const int* __restrict__ rp,
    const int* __restrict__ el, const u16* __restrict__ xp,
    u16* __restrict__ aggt)
{
    const int gid = blockIdx.x * 4 + (threadIdx.x >> 6);
    if (gid >= C1n) return;
    const int lane = threadIdx.x & 63;
    const int b = rp[gid];
    const int e = (gid == C1n - 1) ? NEn : rp[gid + 1];
    float s = 0.f;
    for (int i = b; i < e; i++) {
        const int sr = el[i];
        s += bf2f(xp[(size_t)sr * 64 + lane]);
    }
    const float inv = 1.f / (float)max(e - b, 1);
    aggt[(size_t)gid * 64 + lane] = f2bf(s * inv);
}

// ------- fused layer1: per t { o=[agg_t|x]@[Wl;Wr]+bl; o/=||o|| ; accumulate } ;
//         h1 = LN(relu(sum/3)) written ONCE as bf16. Pure writes, guarded. -------
__global__ __launch_bounds__(256) void k_out1f(const u16* __restrict__ agg3,
    const float* __restrict__ x,
    const float* __restrict__ Wl, const float* __restrict__ Wr,
    const float* __restrict__ bl,
    const float* __restrict__ g0, const float* __restrict__ b0,
    u16* __restrict__ h1)
{
    __shared__ u16 Wt[128 * 136];   // [c][k], pad to 136
    __shared__ float bls[3 * 128], gs[128], bs[128];
    const int tid = threadIdx.x;
    if (tid < 128) { gs[tid] = g0[tid]; bs[tid] = b0[tid]; }
    for (int i = tid; i < 384; i += 256) bls[i] = bl[i];

    const int lane = tid & 63, wid = tid >> 6;
    const int lr = lane & 15, lg = lane >> 4;
    const int ntiles = C1n / 16;                  // 9375
    int rt = blockIdx.x * 4 + wid;
    const bool valid = (rt < ntiles);
    if (rt > ntiles - 1) rt = ntiles - 1;         // clamp for loads only
    const int r0 = rt * 16;

    // x fragments: t-invariant, load once
    bf16x8 xa[2];
    xa[0] = frag8(&x[(size_t)(r0 + lr) * 64 + 0  + 8 * lg]);
    xa[1] = frag8(&x[(size_t)(r0 + lr) * 64 + 32 + 8 * lg]);

    f32x4 hacc[8];
#pragma unroll
    for (int n = 0; n < 8; n++) hacc[n] = 0;

    for (int t = 0; t < 3; t++) {
        __syncthreads();                          // Wt reuse protection
        const float* WlT = Wl + (size_t)t * 64 * 128;
        const float* WrT = Wr + (size_t)t * 64 * 128;
        for (int idx = tid; idx < 128 * 128; idx += 256) {
            int k = idx >> 7, c = idx & 127;
            float w = (k < 64) ? WlT[k * 128 + c] : WrT[(k - 64) * 128 + c];
            Wt[c * 136 + k] = f2bf(w);
        }
        __syncthreads();

        const u16* aggT = agg3 + (size_t)t * C1n * 64;
        f32x4 ta[8];
#pragma unroll
        for (int n = 0; n < 8; n++) ta[n] = 0;
#pragma unroll
        for (int ks = 0; ks < 4; ks++) {
            bf16x8 a;
            if (ks < 2)
                a = *(const bf16x8*)&aggT[(size_t)(r0 + lr) * 64 + ks * 32 + 8 * lg];
            else
                a = xa[ks - 2];
#pragma unroll
            for (int n = 0; n < 8; n++) {
                bf16x8 b = *(const bf16x8*)&Wt[(16 * n + lr) * 136 + ks * 32 + 8 * lg];
                ta[n] = mfma16(a, b, ta[n]);
            }
        }
        // + bias, row L2 norm (row = 4*lg + j; cols spread over 16 lanes x 8 n-tiles)
        float ss[4] = {0.f, 0.f, 0.f, 0.f};
#pragma unroll
        for (int n = 0; n < 8; n++) {
            const float bb = bls[t * 128 + 16 * n + lr];
#pragma unroll
            for (int j = 0; j < 4; j++) {
                ta[n][j] += bb;
                ss[j] += ta[n][j] * ta[n][j];
            }
        }
#pragma unroll
        for (int j = 0; j < 4; j++)
            ss[j] = 1.f / fmaxf(sqrtf(red16(ss[j])), 1e-12f);
#pragma unroll
        for (int n = 0; n < 8; n++)
#pragma unroll
            for (int j = 0; j < 4; j++) hacc[n][j] += ta[n][j] * ss[j];
    }

    // relu + /3 + LayerNorm over 128 cols
    float mu[4] = {0.f, 0.f, 0.f, 0.f};
#pragma unroll
    for (int n = 0; n < 8; n++)
#pragma unroll
        for (int j = 0; j < 4; j++) {
            float v = fmaxf(hacc[n][j], 0.f) * (1.f / 3.f);
            hacc[n][j] = v; mu[j] += v;
        }
#pragma unroll
    for (int j = 0; j < 4; j++) mu[j] = red16(mu[j]) * (1.f / 128.f);
    float var[4] = {0.f, 0.f, 0.f, 0.f};
#pragma unroll
    for (int n = 0; n < 8; n++)
#pragma unroll
        for (int j = 0; j < 4; j++) {
            float d = hacc[n][j] - mu[j]; var[j] += d * d;
        }
#pragma unroll
    for (int j = 0; j < 4; j++) var[j] = rsqrtf(red16(var[j]) * (1.f / 128.f) + 1e-5f);

    if (valid) {
#pragma unroll
        for (int n = 0; n < 8; n++) {
            const float g = gs[16 * n + lr], bb = bs[16 * n + lr];
#pragma unroll
            for (int j = 0; j < 4; j++) {
                float o = (hacc[n][j] - mu[j]) * var[j] * g + bb;
                h1[(size_t)(r0 + 4 * lg + j) * 128 + 16 * n + lr] = f2bf(o);
            }
        }
    }
}

// ---------------- gather layer2: agg2_t[r] = mean of h1[src] (bf16 -> bf16) ----------------
__global__ __launch_bounds__(256) void k_gath2(const int* __restrict__ rp,
    const int* __restrict__ el, const u16* __restrict__ h1,
    u16* __restrict__ agg2t)
{
    const int gid = blockIdx.x * 4 + (threadIdx.x >> 6);
    if (gid >= C0n) return;
    const int lane = threadIdx.x & 63;
    const int b = rp[gid];
    const int e = (gid == C0n - 1) ? E0n : rp[gid + 1];
    float s0 = 0.f, s1 = 0.f;
    for (int i = b; i < e; i++) {
        const int sr = el[i];
        unsigned u = *(const unsigned*)&h1[(size_t)sr * 128 + lane * 2];
        s0 += bf2f((u16)(u & 0xffffu));
        s1 += bf2f((u16)(u >> 16));
    }
    const float inv = 1.f / (float)max(e - b, 1);
    unsigned o = (unsigned)f2bf(s0 * inv) | ((unsigned)f2bf(s1 * inv) << 16);
    *(unsigned*)&agg2t[(size_t)gid * 128 + lane * 2] = o;
}

// ------- fused layer2: acc = sum_t [agg2_t|h1]@[Wl2;Wr2] ; out = LN(relu((acc+Σbl2)/3)) -------
__global__ __launch_bounds__(256) void k_out2f(const u16* __restrict__ agg2,
    const u16* __restrict__ h1,
    const float* __restrict__ Wl2, const float* __restrict__ Wr2,
    const float* __restrict__ bl2,
    const float* __restrict__ g1, const float* __restrict__ b1,
    float* __restrict__ out)
{
    __shared__ u16 Wt[128 * 136];
    __shared__ float bsm[128], gs[128], bs[128];
    const int tid = threadIdx.x;
    if (tid < 128) {
        gs[tid] = g1[tid]; bs[tid] = b1[tid];
        bsm[tid] = bl2[tid] + bl2[128 + tid] + bl2[256 + tid];
    }
    const int lane = tid & 63, wid = tid >> 6;
    const int lr = lane & 15, lg = lane >> 4;
    const int ntiles = C0n / 16;                  // 3125
    int rt = blockIdx.x * 4 + wid;
    const bool valid = (rt < ntiles);
    if (rt > ntiles - 1) rt = ntiles - 1;         // clamp for loads only
    const int r0 = rt * 16;

    // h1 fragments: t-invariant, load once (bf16 direct)
    bf16x8 ha[4];
#pragma unroll
    for (int ks = 0; ks < 4; ks++)
        ha[ks] = *(const bf16x8*)&h1[(size_t)(r0 + lr) * 128 + ks * 32 + 8 * lg];

    f32x4 acc[8];
#pragma unroll
    for (int n = 0; n < 8; n++) acc[n] = 0;

    for (int t = 0; t < 3; t++) {
        for (int hh = 0; hh < 2; hh++) {
            __syncthreads();                      // Wt reuse protection
            const float* W = hh ? Wr2 + (size_t)t * 128 * 128
                                : Wl2 + (size_t)t * 128 * 128;
            for (int idx = tid; idx < 128 * 128; idx += 256) {
                int k = idx >> 7, c = idx & 127;
                Wt[c * 136 + k] = f2bf(W[idx]);   // idx = k*128 + c
            }
            __syncthreads();
#pragma unroll
            for (int ks = 0; ks < 4; ks++) {
                bf16x8 a;
                if (hh == 0)
                    a = *(const bf16x8*)&agg2[(size_t)t * C0n * 128 +
                                              (size_t)(r0 + lr) * 128 + ks * 32 + 8 * lg];
                else
                    a = ha[ks];
#pragma unroll
                for (int n = 0; n < 8; n++) {
                    bf16x8 b = *(const bf16x8*)&Wt[(16 * n + lr) * 136 + ks * 32 + 8 * lg];
                    acc[n] = mfma16(a, b, acc[n]);
                }
            }
        }
    }

    // (acc + Σbias)/3, relu, LN
    float mu[4] = {0.f, 0.f, 0.f, 0.f};
#pragma unroll
    for (int n = 0; n < 8; n++) {
        const float bb = bsm[16 * n + lr];
#pragma unroll
        for (int j = 0; j < 4; j++) {
            float v = fmaxf((acc[n][j] + bb) * (1.f / 3.f), 0.f);
            acc[n][j] = v; mu[j] += v;
        }
    }
#pragma unroll
    for (int j = 0; j < 4; j++) mu[j] = red16(mu[j]) * (1.f / 128.f);
    float var[4] = {0.f, 0.f, 0.f, 0.f};
#pragma unroll
    for (int n = 0; n < 8; n++)
#pragma unroll
        for (int j = 0; j < 4; j++) {
            float d = acc[n][j] - mu[j]; var[j] += d * d;
        }
#pragma unroll
    for (int j = 0; j < 4; j++) var[j] = rsqrtf(red16(var[j]) * (1.f / 128.f) + 1e-5f);

    if (valid) {
#pragma unroll
        for (int n = 0; n < 8; n++) {
            const float g = gs[16 * n + lr], bb = bs[16 * n + lr];
#pragma unroll
            for (int j = 0; j < 4; j++) {
                float o = (acc[n][j] - mu[j]) * var[j] * g + bb;
                out[(size_t)(r0 + 4 * lg + j) * 128 + 16 * n + lr] = o;
            }
        }
    }
}

extern "C" void kernel_launch(void* const* d_in, const int* in_sizes, int n_in,
                              void* d_out, int out_size, void* d_ws, size_t ws_size,
                              hipStream_t stream)
{
    const float* x   = (const float*)d_in[0];
    const int*   ei[3] = { (const int*)d_in[1], (const int*)d_in[2], (const int*)d_in[3] };
    const float* Wp  = (const float*)d_in[6];
    const float* bp  = (const float*)d_in[7];
    const float* Wl  = (const float*)d_in[8];
    const float* bl  = (const float*)d_in[9];
    const float* Wr  = (const float*)d_in[10];
    const float* Wl2 = (const float*)d_in[11];
    const float* bl2 = (const float*)d_in[12];
    const float* Wr2 = (const float*)d_in[13];
    const float* g0  = (const float*)d_in[14];
    const float* b0  = (const float*)d_in[15];
    const float* g1  = (const float*)d_in[16];
    const float* b1  = (const float*)d_in[17];

    // ---- workspace layout (bytes) ----
    char* W = (char*)d_ws;
    u16*   agg3 = (u16*)(W + 0);             // 3*C1*64 bf16 = 57,600,000
    u16*   xp3  = (u16*)(W + 57600000);      // 3*C2*64 bf16 = 115,200,000 -> 172,800,000
    u16*   h1   = (u16*)(W + 57600000);      // C1*128 bf16 = 38,400,000 (overlays xp3, written after gathers)
    int*   rp1  = (int*)(W + 172800000);     // 3*C1*4 = 1,800,000
    int*   fill1= (int*)(W + 174600000);     // 1,800,000
    int*   bsum = (int*)(W + 176400000);     // 4 KiB
    int*   el1  = (int*)(W + 176404096);     // 3*NE*4 = 10,800,000 -> ends 187,204,096
    // layer-2 overlays: agg3 dead after out1f
    u16*   agg2 = (u16*)(W + 0);             // 3*C0*128 bf16 = 38,400,000
    int*   rp2  = (int*)(W + 38400000);      // 600,000
    int*   fill2= (int*)(W + 39000000);      // 600,000
    int*   el2  = (int*)(W + 39600000);      // 3*E0*4 = 3,600,000 -> ends 43,200,000

    const int nb1 = (C1n + 2047) / 2048;  // 74
    const int nb2 = (C0n + 2047) / 2048;  // 25

    // ---- CSR layer 1 (dst over full edge list, nV=C1) ----
    hipMemsetAsync(rp1, 0, 2 * 3 * (size_t)C1n * 4, stream);   // rp1 + fill1
    k_hist<<<dim3((NEn + 255) / 256, 3), 256, 0, stream>>>(
        ei[0] + NEn, ei[1] + NEn, ei[2] + NEn, rp1, NEn, C1n);
    k_scan_a<<<dim3(nb1, 3), 256, 0, stream>>>(rp1, C1n, bsum, nb1);
    k_scan_b<<<dim3(1, 3), 256, 0, stream>>>(bsum, nb1);
    k_scan_c<<<dim3(nb1, 3), 256, 0, stream>>>(rp1, C1n, bsum, nb1);
    k_fill<<<dim3((NEn + 255) / 256, 3), 256, 0, stream>>>(
        ei[0], ei[1], ei[2], ei[0] + NEn, ei[1] + NEn, ei[2] + NEn,
        rp1, fill1, el1, NEn, C1n);

    // ---- layer 1: one proj for all t, gathers, fused out+LN ----
    k_projm3<<<(C2n / 16 + 3) / 4, 256, 0, stream>>>(x, Wp, bp, xp3);
    for (int t = 0; t < 3; t++)
        k_gath1<<<(C1n + 3) / 4, 256, 0, stream>>>(rp1 + (size_t)t * C1n,
                                                   el1 + (size_t)t * NEn,
                                                   xp3 + (size_t)t * C2n * 64,
                                                   agg3 + (size_t)t * C1n * 64);
    k_out1f<<<(C1n / 16 + 3) / 4, 256, 0, stream>>>(agg3, x, Wl, Wr, bl, g0, b0, h1);

    // ---- CSR layer 2 (first E0 edges, nV=C0) ----
    hipMemsetAsync(rp2, 0, 2 * 3 * (size_t)C0n * 4, stream);   // rp2 + fill2
    k_hist<<<dim3((E0n + 255) / 256, 3), 256, 0, stream>>>(
        ei[0] + NEn, ei[1] + NEn, ei[2] + NEn, rp2, E0n, C0n);
    k_scan_a<<<dim3(nb2, 3), 256, 0, stream>>>(rp2, C0n, bsum, nb2);
    k_scan_b<<<dim3(1, 3), 256, 0, stream>>>(bsum, nb2);
    k_scan_c<<<dim3(nb2, 3), 256, 0, stream>>>(rp2, C0n, bsum, nb2);
    k_fill<<<dim3((E0n + 255) / 256, 3), 256, 0, stream>>>(
        ei[0], ei[1], ei[2], ei[0] + NEn, ei[1] + NEn, ei[2] + NEn,
        rp2, fill2, el2, E0n, C0n);

    // ---- layer 2: gathers, fused out+LN -> d_out ----
    for (int t = 0; t < 3; t++)
        k_gath2<<<(C0n + 3) / 4, 256, 0, stream>>>(rp2 + (size_t)t * C0n,
                                                   el2 + (size_t)t * E0n, h1,
                                                   agg2 + (size_t)t * C0n * 128);
    k_out2f<<<(C0n / 16 + 3) / 4, 256, 0, stream>>>(agg2, h1, Wl2, Wr2, bl2, g1, b1,
                                                    (float*)d_out);
}